// Round 17
// baseline (113.548 us; speedup 1.0000x reference)
//
#include <hip/hip_runtime.h>
#include <hip/hip_bf16.h>
#include <math.h>

typedef __attribute__((ext_vector_type(4))) float f32x4;
typedef __attribute__((ext_vector_type(8))) short short8;
typedef __attribute__((ext_vector_type(8))) unsigned short ushort8;
typedef __attribute__((ext_vector_type(4))) unsigned short ushort4v;

__device__ __forceinline__ unsigned short f2bf(float f) {
  __hip_bfloat16 h = __float2bfloat16(f);
  return *reinterpret_cast<unsigned short*>(&h);
}
__device__ __forceinline__ float bf2f(unsigned short u) {
  unsigned v = ((unsigned)u) << 16;
  return *reinterpret_cast<float*>(&v);
}
__device__ __forceinline__ void async16(const void* g, void* l) {
  __builtin_amdgcn_global_load_lds(
      (__attribute__((address_space(1))) void*)g,
      (__attribute__((address_space(3))) void*)l, 16, 0, 0);
}

// ---------------- fused prep: RoPE tables + all f32->bf16 casts + sr_w repack ----------------
__global__ __launch_bounds__(256) void k_prep(
    const float* __restrict__ x, const float* __restrict__ Wq,
    const float* __restrict__ Wkv, const float* __restrict__ pw,
    const float* __restrict__ srw,
    float* __restrict__ qtab, float* __restrict__ ktab,
    unsigned short* __restrict__ xb, unsigned short* __restrict__ wqb,
    unsigned short* __restrict__ wkvb, unsigned short* __restrict__ pwb,
    unsigned short* __restrict__ wsrb)
{
  int idx = blockIdx.x * 256 + threadIdx.x;
  if (idx < 131072) {                       // q-table [4096][32]
    int n = idx >> 5, i = idx & 31;
    float freq = powf(10000.0f, -(float)(i >> 1) * (1.0f / 16.0f));
    float pos = (i & 1) ? (float)(n >> 6) : (float)(n & 63);
    float a = pos * freq;
    qtab[idx * 2] = cosf(a);
    qtab[idx * 2 + 1] = sinf(a);
  } else if (idx < 163840) {                // k-table [1024][32]
    int t = idx - 131072;
    int m = t >> 5, i = t & 31;
    float freq = powf(10000.0f, -(float)(i >> 1) * (1.0f / 16.0f));
    float pos = (i & 1) ? (0.5f + 2.0f * (float)(m >> 6)) : (0.5f + 2.0f * (float)(m & 63));
    float a = pos * freq;
    ktab[t * 2] = cosf(a);
    ktab[t * 2 + 1] = sinf(a);
  } else if (idx < 1736704) {               // x cvt (float4 units)
    int g = idx - 163840;
    float4 v = ((const float4*)x)[g];
    ushort4v o; o[0]=f2bf(v.x); o[1]=f2bf(v.y); o[2]=f2bf(v.z); o[3]=f2bf(v.w);
    *(ushort4v*)(xb + g * 4) = o;
  } else if (idx < 1884160) {               // Wq cvt
    int g = idx - 1736704;
    float4 v = ((const float4*)Wq)[g];
    ushort4v o; o[0]=f2bf(v.x); o[1]=f2bf(v.y); o[2]=f2bf(v.z); o[3]=f2bf(v.w);
    *(ushort4v*)(wqb + g * 4) = o;
  } else if (idx < 2179072) {               // Wkv cvt
    int g = idx - 1884160;
    float4 v = ((const float4*)Wkv)[g];
    ushort4v o; o[0]=f2bf(v.x); o[1]=f2bf(v.y); o[2]=f2bf(v.z); o[3]=f2bf(v.w);
    *(ushort4v*)(wkvb + g * 4) = o;
  } else if (idx < 2326528) {               // proj_w cvt
    int g = idx - 2179072;
    float4 v = ((const float4*)pw)[g];
    ushort4v o; o[0]=f2bf(v.x); o[1]=f2bf(v.y); o[2]=f2bf(v.z); o[3]=f2bf(v.w);
    *(ushort4v*)(pwb + g * 4) = o;
  } else if (idx < 4685824) {               // sr_w (O,C,2,2) -> [patch][O][C]
    int g = idx - 2326528;
    int o = g / 3072;
    int rem = g - o * 3072;
    int c = rem >> 2, patch = rem & 3;
    wsrb[(size_t)patch * 589824 + o * 768 + c] = f2bf(srw[g]);
  }
}

// ---------------- GEMM, 128x128 tile, BK=64 (128-B staging segments), 2-buffer ----------------
// Request-floor staging (proven r16): BK=64 rows are exactly one 128-B cache line;
// each 1-KB wave instruction = 8 line requests (the minimum). Linear LDS dest +
// pre-swizzled global source chunk + matching XOR on LDS reads (rule #21).
// MODE 0: proj (384) f32+bias -> d_out | MODE 1: kv (192) RoPE-K->kr, V->vr
// MODE 2: Q    (384) RoPE-Q -> qrope   | MODE 3: conv (384 = 96 tiles x 4 patches) -> part
template<int MODE>
__global__ __launch_bounds__(256) void k_g(
    const unsigned short* __restrict__ A, const unsigned short* __restrict__ W,
    void* __restrict__ O0, void* __restrict__ O1,
    const float* __restrict__ bias, const float* __restrict__ tab)
{
  __shared__ __align__(16) unsigned short As[2][128][64];   // 32 KB
  __shared__ __align__(16) unsigned short Ws[2][128][64];   // 32 KB
  const int tid = threadIdx.x, lane = tid & 63, wid = tid >> 6;
  const int wr = (wid >> 1) * 64, wc = (wid & 1) * 64;
  const int l15 = lane & 15, lhi = lane >> 4;
  const int K = 768, NT = 12;

  // XCD-chunked bijective swizzle (grid % 8 == 0 for all modes)
  const int NWG = (MODE == 1) ? 192 : 384;
  const int tile = ((int)blockIdx.x & 7) * (NWG >> 3) + ((int)blockIdx.x >> 3);

  int cm, cn, patch = 0;
  if (MODE == 3) {
    patch = tile / 96; int r = tile - patch * 96;
    cm = (r / 6) * 128; cn = (r % 6) * 128;
  } else if (MODE == 1) {
    cm = (tile / 12) * 128; cn = (tile % 12) * 128;
  } else {
    cm = (tile / 6) * 128; cn = (tile % 6) * 128;
  }

  // staging: wave covers A rows [wid*32,+32) and W rows [wid*32,+32); 4 instrs each,
  // 8 rows (= 1024 contiguous LDS bytes) per instr. Source chunk pre-swizzled:
  const int swz = ((lane & 7) * 8) ^ ((lane >> 3) << 3);   // elements, within 64-elem row
  size_t aoff[4], woff[4];
  #pragma unroll
  for (int c = 0; c < 4; c++) {
    int r = cm + wid * 32 + c * 8 + (lane >> 3);
    if (MODE == 3) {
      int kh = patch >> 1, kw = patch & 1;
      int bb = r >> 10, p = r & 1023;
      r = bb * 4096 + (2 * (p >> 5) + kh) * 64 + 2 * (p & 31) + kw;
    }
    aoff[c] = (size_t)r * K + swz;
  }
  #pragma unroll
  for (int c = 0; c < 4; c++)
    woff[c] = (size_t)(cn + wid * 32 + c * 8 + (lane >> 3)) * K + swz;
  const unsigned short* wbase = (MODE == 3) ? (W + (size_t)patch * 589824) : W;

#define STAGE(bi, kt) { \
    _Pragma("unroll") for (int c = 0; c < 4; c++) \
      async16(A + aoff[c] + (kt) * 64, &As[bi][wid * 32 + c * 8][0]); \
    _Pragma("unroll") for (int c = 0; c < 4; c++) \
      async16(wbase + woff[c] + (kt) * 64, &Ws[bi][wid * 32 + c * 8][0]); }

  f32x4 zero = {0.f, 0.f, 0.f, 0.f};
  f32x4 acc[4][4];
  #pragma unroll
  for (int i = 0; i < 4; i++)
    #pragma unroll
    for (int j = 0; j < 4; j++) acc[i][j] = zero;

  STAGE(0, 0);

  const int rswzA = (l15 & 7) << 3;   // read-side XOR (row&7)<<3 elements
  for (int kt = 0; kt < NT; ++kt) {
    __syncthreads();                      // stage(kt) landed; prior reads done
    const int bi = kt & 1;
    if (kt + 1 < NT) STAGE(bi ^ 1, kt + 1);
    #pragma unroll
    for (int h = 0; h < 2; h++) {
      short8 af[4], wf[4];
      #pragma unroll
      for (int m = 0; m < 4; m++)
        af[m] = *(const short8*)&As[bi][wr + m * 16 + l15][(h * 32 + lhi * 8) ^ rswzA];
      #pragma unroll
      for (int n = 0; n < 4; n++)
        wf[n] = *(const short8*)&Ws[bi][wc + n * 16 + l15][(h * 32 + lhi * 8) ^ rswzA];
      #pragma unroll
      for (int m = 0; m < 4; m++)
        #pragma unroll
        for (int n = 0; n < 4; n++)
          acc[m][n] = __builtin_amdgcn_mfma_f32_16x16x32_bf16(wf[n], af[m], acc[m][n], 0, 0, 0);
    }
  }
#undef STAGE

  // swapped layout: acc[m][n][r] = out[row = cm+wr+m*16+l15][col = cn+wc+n*16+lhi*4+r]
  if (MODE == 0) {
    float* O = (float*)O0;
    #pragma unroll
    for (int n = 0; n < 4; n++) {
      int colb = cn + wc + n * 16 + lhi * 4;
      f32x4 bv = *(const f32x4*)&bias[colb];
      #pragma unroll
      for (int m = 0; m < 4; m++) {
        int row = cm + wr + m * 16 + l15;
        f32x4 v = acc[m][n] + bv;
        *(f32x4*)&O[(size_t)row * 768 + colb] = v;
      }
    }
  } else if (MODE == 2) {
    // RoPE-Q: pairs (2i,2i+1) in-lane -> packed 8B stores
    unsigned short* qr = (unsigned short*)O0;
    const float2* t2 = (const float2*)tab;
    #pragma unroll
    for (int n = 0; n < 4; n++) {
      int col = cn + wc + n * 16 + lhi * 4;
      int hh = col >> 6, d0 = col & 63, i0 = d0 >> 1;
      #pragma unroll
      for (int m = 0; m < 4; m++) {
        int row = cm + wr + m * 16 + l15;
        int bb = row >> 12, np = row & 4095;
        float2 cs0 = t2[np * 32 + i0];
        float2 cs1 = t2[np * 32 + i0 + 1];
        f32x4 v = acc[m][n];
        ushort4v o;
        o[0] = f2bf(v[0] * cs0.x - v[1] * cs0.y);
        o[1] = f2bf(v[0] * cs0.y + v[1] * cs0.x);
        o[2] = f2bf(v[2] * cs1.x - v[3] * cs1.y);
        o[3] = f2bf(v[2] * cs1.y + v[3] * cs1.x);
        *(ushort4v*)(qr + ((size_t)(bb * 12 + hh) * 4096 + np) * 64 + d0) = o;
      }
    }
  } else if (MODE == 1) {
    // cols 0..767 -> K (RoPE, in-lane pairs), 768..1535 -> V (plain pack)
    unsigned short* kr = (unsigned short*)O0;
    unsigned short* vr = (unsigned short*)O1;
    const float2* t2 = (const float2*)tab;
    #pragma unroll
    for (int n = 0; n < 4; n++) {
      int col = cn + wc + n * 16 + lhi * 4;
      bool isk = (col < 768);
      int c2 = isk ? col : col - 768;
      int hh = c2 >> 6, d0 = c2 & 63, i0 = d0 >> 1;
      #pragma unroll
      for (int m = 0; m < 4; m++) {
        int row = cm + wr + m * 16 + l15;
        int bb = row >> 10, mm = row & 1023;
        f32x4 v = acc[m][n];
        size_t o = ((size_t)(bb * 12 + hh) * 1024 + mm) * 64 + d0;
        ushort4v pk;
        if (isk) {
          float2 cs0 = t2[mm * 32 + i0];
          float2 cs1 = t2[mm * 32 + i0 + 1];
          pk[0] = f2bf(v[0] * cs0.x - v[1] * cs0.y);
          pk[1] = f2bf(v[0] * cs0.y + v[1] * cs0.x);
          pk[2] = f2bf(v[2] * cs1.x - v[3] * cs1.y);
          pk[3] = f2bf(v[2] * cs1.y + v[3] * cs1.x);
          *(ushort4v*)(kr + o) = pk;
        } else {
          pk[0] = f2bf(v[0]); pk[1] = f2bf(v[1]);
          pk[2] = f2bf(v[2]); pk[3] = f2bf(v[3]);
          *(ushort4v*)(vr + o) = pk;
        }
      }
    }
  } else {
    // conv partial: plain bf16 pack, 8B stores
    unsigned short* O = (unsigned short*)O0 + (size_t)patch * 2048 * 768;
    #pragma unroll
    for (int n = 0; n < 4; n++) {
      int colb = cn + wc + n * 16 + lhi * 4;
      #pragma unroll
      for (int m = 0; m < 4; m++) {
        int row = cm + wr + m * 16 + l15;
        f32x4 v = acc[m][n];
        ushort4v pk;
        pk[0] = f2bf(v[0]); pk[1] = f2bf(v[1]);
        pk[2] = f2bf(v[2]); pk[3] = f2bf(v[3]);
        *(ushort4v*)(O + (size_t)row * 768 + colb) = pk;
      }
    }
  }
}

// ---------------- fused partial-reduce + bias + LayerNorm -> bf16 ----------------
__global__ __launch_bounds__(256) void k_lnr(const unsigned short* __restrict__ part,
    const float* __restrict__ srb, const float* __restrict__ g,
    const float* __restrict__ b, unsigned short* __restrict__ out) {
  int row = blockIdx.x;
  int t = threadIdx.x;
  float v[3];
  #pragma unroll
  for (int j = 0; j < 3; j++) {
    int c = t + j * 256;
    float s = srb[c];
    #pragma unroll
    for (int p = 0; p < 4; p++)
      s += bf2f(part[((size_t)p * 2048 + row) * 768 + c]);
    v[j] = s;
  }
  float s = v[0] + v[1] + v[2];
  float s2 = v[0] * v[0] + v[1] * v[1] + v[2] * v[2];
  #pragma unroll
  for (int off = 1; off < 64; off <<= 1) {
    s += __shfl_xor(s, off);
    s2 += __shfl_xor(s2, off);
  }
  __shared__ float ss[4], ss2[4];
  int w = t >> 6;
  if ((t & 63) == 0) { ss[w] = s; ss2[w] = s2; }
  __syncthreads();
  s = ss[0] + ss[1] + ss[2] + ss[3];
  s2 = ss2[0] + ss2[1] + ss2[2] + ss2[3];
  float mu = s * (1.0f / 768.0f);
  float var = s2 * (1.0f / 768.0f) - mu * mu;
  float rstd = rsqrtf(var + 1e-5f);
  unsigned short* o = out + (size_t)row * 768;
  #pragma unroll
  for (int j = 0; j < 3; j++) {
    int c = t + j * 256;
    o[c] = f2bf((v[j] - mu) * rstd * g[c] + b[c]);
  }
}

// ---------------- masked attention: per (b,h,128-query block), bf16 out ----------------
// K/V staged ONCE per 128 queries (2 q-tiles per block, halves K/V staging vs r16);
// V staging vectorized (ushort8 global reads, LDS scatter).
__global__ __launch_bounds__(256) void k_attn(
    const unsigned short* __restrict__ qr,
    const unsigned short* __restrict__ kr,
    const unsigned short* __restrict__ vr,
    unsigned short* __restrict__ aout)
{
  __shared__ __align__(16) unsigned short kt_s[96][72];
  __shared__ __align__(16) unsigned short vt_s[64][104];
  __shared__ __align__(16) unsigned short p_s[4][16][104];

  const int qb = blockIdx.x;               // 32 blocks of 128 queries
  const int h = blockIdx.y;
  const int b = blockIdx.z;
  const int bh = b * 12 + h;
  const int tid = threadIdx.x, lane = tid & 63, w = tid >> 6;
  const int l15 = lane & 15, lhi = lane >> 4;

  const unsigned short* kg = kr + (size_t)bh * 1024 * 64;
  #pragma unroll
  for (int it = 0; it < 3; it++) {
    int ch = it * 256 + tid;
    int row = ch >> 3, c8 = (ch & 7) * 8;
    *(ushort8*)&kt_s[row][c8] = *(const ushort8*)(kg + row * 64 + c8);
  }
  const unsigned short* vg = vr + (size_t)bh * 1024 * 64;
  #pragma unroll
  for (int it = 0; it < 3; it++) {
    int ch = it * 256 + tid;                 // 768 chunks: row = ch>>3, d0 = (ch&7)*8
    int row = ch >> 3, d0 = (ch & 7) * 8;
    ushort8 vv = *(const ushort8*)(vg + row * 64 + d0);
    #pragma unroll
    for (int j = 0; j < 8; j++) vt_s[d0 + j][row] = vv[j];
  }
  __syncthreads();

  f32x4 zero = {0.f, 0.f, 0.f, 0.f};

  #pragma unroll
  for (int q2 = 0; q2 < 2; ++q2) {
    const int qt = qb * 2 + q2;              // 64-query tile index

    const unsigned short* qg = qr + (size_t)bh * 4096 * 64
                             + (size_t)(qt * 64 + w * 16 + l15) * 64 + lhi * 8;
    short8 qf0 = *(const short8*)qg;
    short8 qf1 = *(const short8*)(qg + 32);

    f32x4 sacc[6];
    #pragma unroll
    for (int g = 0; g < 6; g++) sacc[g] = zero;
    #pragma unroll
    for (int g = 0; g < 6; g++) {
      short8 kf0 = *(const short8*)&kt_s[g * 16 + l15][lhi * 8];
      short8 kf1 = *(const short8*)&kt_s[g * 16 + l15][32 + lhi * 8];
      sacc[g] = __builtin_amdgcn_mfma_f32_16x16x32_bf16(qf0, kf0, sacc[g], 0, 0, 0);
      sacc[g] = __builtin_amdgcn_mfma_f32_16x16x32_bf16(qf1, kf1, sacc[g], 0, 0, 0);
    }

    int visv[4];
    #pragma unroll
    for (int r = 0; r < 4; r++) {
      int n = qt * 64 + w * 16 + lhi * 4 + r;
      visv[r] = 2 * (n >> 7) + (((n >> 6) + ((n & 63) << 6)) >> 7) + 1;
    }

    float mx[4] = {-INFINITY, -INFINITY, -INFINITY, -INFINITY};
    #pragma unroll
    for (int g = 0; g < 6; g++) {
      int key = g * 16 + l15;
      #pragma unroll
      for (int r = 0; r < 4; r++) {
        float s = (key < visv[r]) ? sacc[g][r] * 0.125f : -INFINITY;
        sacc[g][r] = s;
        mx[r] = fmaxf(mx[r], s);
      }
    }
    #pragma unroll
    for (int off = 1; off < 16; off <<= 1) {
      #pragma unroll
      for (int r = 0; r < 4; r++) mx[r] = fmaxf(mx[r], __shfl_xor(mx[r], off));
    }
    float sum[4] = {0.f, 0.f, 0.f, 0.f};
    #pragma unroll
    for (int g = 0; g < 6; g++) {
      #pragma unroll
      for (int r = 0; r < 4; r++) {
        float pv = __expf(sacc[g][r] - mx[r]);
        sum[r] += pv;
        p_s[w][lhi * 4 + r][g * 16 + l15] = f2bf(pv);
      }
    }
    #pragma unroll
    for (int off = 1; off < 16; off <<= 1) {
      #pragma unroll
      for (int r = 0; r < 4; r++) sum[r] += __shfl_xor(sum[r], off);
    }

    f32x4 oacc[4];
    #pragma unroll
    for (int dg = 0; dg < 4; dg++) oacc[dg] = zero;
    #pragma unroll
    for (int ks = 0; ks < 3; ks++) {
      short8 pa = *(const short8*)&p_s[w][l15][ks * 32 + lhi * 8];
      #pragma unroll
      for (int dg = 0; dg < 4; dg++) {
        short8 vb = *(const short8*)&vt_s[dg * 16 + l15][ks * 32 + lhi * 8];
        oacc[dg] = __builtin_amdgcn_mfma_f32_16x16x32_bf16(pa, vb, oacc[dg], 0, 0, 0);
      }
    }

    unsigned short* ob = aout + ((size_t)b * 4096 + qt * 64 + w * 16) * 768 + h * 64;
    #pragma unroll
    for (int dg = 0; dg < 4; dg++) {
      int d = dg * 16 + l15;
      #pragma unroll
      for (int r = 0; r < 4; r++) {
        ob[(size_t)(lhi * 4 + r) * 768 + d] = f2bf(oacc[dg][r] / sum[r]);
      }
    }
  }
}

extern "C" void kernel_launch(void* const* d_in, const int* in_sizes, int n_in,
                              void* d_out, int out_size, void* d_ws, size_t ws_size,
                              hipStream_t stream) {
  const float* x   = (const float*)d_in[0];
  const float* Wq  = (const float*)d_in[1];
  const float* Wkv = (const float*)d_in[2];
  const float* srw = (const float*)d_in[3];
  const float* srb = (const float*)d_in[4];
  const float* lng = (const float*)d_in[5];
  const float* lnb = (const float*)d_in[6];
  const float* pw  = (const float*)d_in[7];
  const float* pb  = (const float*)d_in[8];

  char* ws = (char*)d_ws;
  float* qtab           = (float*)(ws);
  float* ktab           = (float*)(ws + 1048576);
  unsigned short* xb    = (unsigned short*)(ws + 1310720);    // bf16 x; attn_out later
  unsigned short* attno = xb;
  unsigned short* qrope = (unsigned short*)(ws + 13893632);
  unsigned short* part  = (unsigned short*)(ws + 26476544);   // [4][2048][768] bf16
  unsigned short* kr    = (unsigned short*)(ws + 26476544);   // overlays part (dead)
  unsigned short* vr    = (unsigned short*)(ws + 29622272);
  unsigned short* wqb   = (unsigned short*)(ws + 39059456);
  unsigned short* wkvb  = (unsigned short*)(ws + 40239104);
  unsigned short* pwb   = (unsigned short*)(ws + 42598400);
  unsigned short* wsrb  = (unsigned short*)(ws + 43778048);   // [4][768][768] bf16
  unsigned short* xrn   = (unsigned short*)(ws + 48496640);   // [2048][768] bf16

  k_prep<<<18304, 256, 0, stream>>>(x, Wq, Wkv, pw, srw, qtab, ktab,
                                    xb, wqb, wkvb, pwb, wsrb);
  k_g<2><<<384, 256, 0, stream>>>(xb, wqb, qrope, nullptr, nullptr, qtab);
  k_g<3><<<384, 256, 0, stream>>>(xb, wsrb, part, nullptr, nullptr, nullptr);
  k_lnr<<<2048, 256, 0, stream>>>(part, srb, lng, lnb, xrn);
  k_g<1><<<192, 256, 0, stream>>>(xrn, wkvb, kr, vr, nullptr, ktab);
  k_attn<<<dim3(32, 12, 2), 256, 0, stream>>>(qrope, kr, vr, attno);
  k_g<0><<<384, 256, 0, stream>>>(attno, pwb, d_out, nullptr, pb, nullptr);
}

// Round 18
// 104.598 us; speedup vs baseline: 1.0856x; 1.0856x over previous
//
#include <hip/hip_runtime.h>
#include <hip/hip_bf16.h>
#include <math.h>

typedef __attribute__((ext_vector_type(4))) float f32x4;
typedef __attribute__((ext_vector_type(8))) short short8;
typedef __attribute__((ext_vector_type(8))) unsigned short ushort8;
typedef __attribute__((ext_vector_type(4))) unsigned short ushort4v;

__device__ __forceinline__ unsigned short f2bf(float f) {
  __hip_bfloat16 h = __float2bfloat16(f);
  return *reinterpret_cast<unsigned short*>(&h);
}
__device__ __forceinline__ float bf2f(unsigned short u) {
  unsigned v = ((unsigned)u) << 16;
  return *reinterpret_cast<float*>(&v);
}
__device__ __forceinline__ void async16(const void* g, void* l) {
  __builtin_amdgcn_global_load_lds(
      (__attribute__((address_space(1))) void*)g,
      (__attribute__((address_space(3))) void*)l, 16, 0, 0);
}
#define WAITVM8 { asm volatile("s_waitcnt vmcnt(8)" ::: "memory"); __builtin_amdgcn_sched_barrier(0); }
#define WAITVM0 { asm volatile("s_waitcnt vmcnt(0)" ::: "memory"); __builtin_amdgcn_sched_barrier(0); }

// ---------------- fused prep: RoPE tables + all f32->bf16 casts + sr_w repack ----------------
__global__ __launch_bounds__(256) void k_prep(
    const float* __restrict__ x, const float* __restrict__ Wq,
    const float* __restrict__ Wkv, const float* __restrict__ pw,
    const float* __restrict__ srw,
    float* __restrict__ qtab, float* __restrict__ ktab,
    unsigned short* __restrict__ xb, unsigned short* __restrict__ wqb,
    unsigned short* __restrict__ wkvb, unsigned short* __restrict__ pwb,
    unsigned short* __restrict__ wsrb)
{
  int idx = blockIdx.x * 256 + threadIdx.x;
  if (idx < 131072) {                       // q-table [4096][32]
    int n = idx >> 5, i = idx & 31;
    float freq = powf(10000.0f, -(float)(i >> 1) * (1.0f / 16.0f));
    float pos = (i & 1) ? (float)(n >> 6) : (float)(n & 63);
    float a = pos * freq;
    qtab[idx * 2] = cosf(a);
    qtab[idx * 2 + 1] = sinf(a);
  } else if (idx < 163840) {                // k-table [1024][32]
    int t = idx - 131072;
    int m = t >> 5, i = t & 31;
    float freq = powf(10000.0f, -(float)(i >> 1) * (1.0f / 16.0f));
    float pos = (i & 1) ? (0.5f + 2.0f * (float)(m >> 6)) : (0.5f + 2.0f * (float)(m & 63));
    float a = pos * freq;
    ktab[t * 2] = cosf(a);
    ktab[t * 2 + 1] = sinf(a);
  } else if (idx < 1736704) {               // x cvt (float4 units)
    int g = idx - 163840;
    float4 v = ((const float4*)x)[g];
    ushort4v o; o[0]=f2bf(v.x); o[1]=f2bf(v.y); o[2]=f2bf(v.z); o[3]=f2bf(v.w);
    *(ushort4v*)(xb + g * 4) = o;
  } else if (idx < 1884160) {               // Wq cvt
    int g = idx - 1736704;
    float4 v = ((const float4*)Wq)[g];
    ushort4v o; o[0]=f2bf(v.x); o[1]=f2bf(v.y); o[2]=f2bf(v.z); o[3]=f2bf(v.w);
    *(ushort4v*)(wqb + g * 4) = o;
  } else if (idx < 2179072) {               // Wkv cvt
    int g = idx - 1884160;
    float4 v = ((const float4*)Wkv)[g];
    ushort4v o; o[0]=f2bf(v.x); o[1]=f2bf(v.y); o[2]=f2bf(v.z); o[3]=f2bf(v.w);
    *(ushort4v*)(wkvb + g * 4) = o;
  } else if (idx < 2326528) {               // proj_w cvt
    int g = idx - 2179072;
    float4 v = ((const float4*)pw)[g];
    ushort4v o; o[0]=f2bf(v.x); o[1]=f2bf(v.y); o[2]=f2bf(v.z); o[3]=f2bf(v.w);
    *(ushort4v*)(pwb + g * 4) = o;
  } else if (idx < 4685824) {               // sr_w (O,C,2,2) -> [patch][O][C]
    int g = idx - 2326528;
    int o = g / 3072;
    int rem = g - o * 3072;
    int c = rem >> 2, patch = rem & 3;
    wsrb[(size_t)patch * 589824 + o * 768 + c] = f2bf(srw[g]);
  }
}

// ---------------- GEMM, 128x128 tile, BK=64 (128-B lines), 2-buffer counted-vmcnt ----------------
// r16's request-floor staging + overlapped stage: issue stage(kt+1) then wait vmcnt(8)
// (stage(kt) landed, stage(kt+1) flies across the compute phase). Two raw barriers/step:
// first joins prior readers of the target buffer, second joins stage(kt) completion.
// MODE 0: proj (384) f32+bias -> d_out | MODE 1: kv (192) RoPE-K->kr, V->vr
// MODE 2: Q    (384) RoPE-Q -> qrope   | MODE 3: conv (384 = 96 tiles x 4 patches) -> part
template<int MODE>
__global__ __launch_bounds__(256) void k_g(
    const unsigned short* __restrict__ A, const unsigned short* __restrict__ W,
    void* __restrict__ O0, void* __restrict__ O1,
    const float* __restrict__ bias, const float* __restrict__ tab)
{
  __shared__ __align__(16) unsigned short As[2][128][64];   // 32 KB
  __shared__ __align__(16) unsigned short Ws[2][128][64];   // 32 KB
  const int tid = threadIdx.x, lane = tid & 63, wid = tid >> 6;
  const int wr = (wid >> 1) * 64, wc = (wid & 1) * 64;
  const int l15 = lane & 15, lhi = lane >> 4;
  const int K = 768, NT = 12;

  // XCD-chunked bijective swizzle (grid % 8 == 0 for all modes)
  const int NWG = (MODE == 1) ? 192 : 384;
  const int tile = ((int)blockIdx.x & 7) * (NWG >> 3) + ((int)blockIdx.x >> 3);

  int cm, cn, patch = 0;
  if (MODE == 3) {
    patch = tile / 96; int r = tile - patch * 96;
    cm = (r / 6) * 128; cn = (r % 6) * 128;
  } else if (MODE == 1) {
    cm = (tile / 12) * 128; cn = (tile % 12) * 128;
  } else {
    cm = (tile / 6) * 128; cn = (tile % 6) * 128;
  }

  // staging: wave covers A rows [wid*32,+32) and W rows [wid*32,+32); 4 instrs each,
  // 8 rows (= 1024 contiguous LDS bytes) per instr. Source chunk pre-swizzled:
  const int swz = ((lane & 7) * 8) ^ ((lane >> 3) << 3);   // elements, within 64-elem row
  size_t aoff[4], woff[4];
  #pragma unroll
  for (int c = 0; c < 4; c++) {
    int r = cm + wid * 32 + c * 8 + (lane >> 3);
    if (MODE == 3) {
      int kh = patch >> 1, kw = patch & 1;
      int bb = r >> 10, p = r & 1023;
      r = bb * 4096 + (2 * (p >> 5) + kh) * 64 + 2 * (p & 31) + kw;
    }
    aoff[c] = (size_t)r * K + swz;
  }
  #pragma unroll
  for (int c = 0; c < 4; c++)
    woff[c] = (size_t)(cn + wid * 32 + c * 8 + (lane >> 3)) * K + swz;
  const unsigned short* wbase = (MODE == 3) ? (W + (size_t)patch * 589824) : W;

#define STAGE(bi, kt) { \
    _Pragma("unroll") for (int c = 0; c < 4; c++) \
      async16(A + aoff[c] + (kt) * 64, &As[bi][wid * 32 + c * 8][0]); \
    _Pragma("unroll") for (int c = 0; c < 4; c++) \
      async16(wbase + woff[c] + (kt) * 64, &Ws[bi][wid * 32 + c * 8][0]); }

  f32x4 zero = {0.f, 0.f, 0.f, 0.f};
  f32x4 acc[4][4];
  #pragma unroll
  for (int i = 0; i < 4; i++)
    #pragma unroll
    for (int j = 0; j < 4; j++) acc[i][j] = zero;

  STAGE(0, 0);

  const int rswzA = (l15 & 7) << 3;   // read-side XOR (row&7)<<3 elements
  for (int kt = 0; kt < NT; ++kt) {
    const int bi = kt & 1;
    __builtin_amdgcn_s_barrier();        // all waves done reading buffer bi^1 (iter kt-1)
    if (kt + 1 < NT) {
      STAGE(bi ^ 1, kt + 1);             // issue next stage early; flies across compute
      WAITVM8                            // own stage(kt) landed (8 newer may fly)
    } else {
      WAITVM0
    }
    __builtin_amdgcn_s_barrier();        // all waves' stage(kt) landed
    __builtin_amdgcn_sched_barrier(0);
    #pragma unroll
    for (int h = 0; h < 2; h++) {
      short8 af[4], wf[4];
      #pragma unroll
      for (int m = 0; m < 4; m++)
        af[m] = *(const short8*)&As[bi][wr + m * 16 + l15][(h * 32 + lhi * 8) ^ rswzA];
      #pragma unroll
      for (int n = 0; n < 4; n++)
        wf[n] = *(const short8*)&Ws[bi][wc + n * 16 + l15][(h * 32 + lhi * 8) ^ rswzA];
      #pragma unroll
      for (int m = 0; m < 4; m++)
        #pragma unroll
        for (int n = 0; n < 4; n++)
          acc[m][n] = __builtin_amdgcn_mfma_f32_16x16x32_bf16(wf[n], af[m], acc[m][n], 0, 0, 0);
    }
  }
#undef STAGE

  // swapped layout: acc[m][n][r] = out[row = cm+wr+m*16+l15][col = cn+wc+n*16+lhi*4+r]
  if (MODE == 0) {
    float* O = (float*)O0;
    #pragma unroll
    for (int n = 0; n < 4; n++) {
      int colb = cn + wc + n * 16 + lhi * 4;
      f32x4 bv = *(const f32x4*)&bias[colb];
      #pragma unroll
      for (int m = 0; m < 4; m++) {
        int row = cm + wr + m * 16 + l15;
        f32x4 v = acc[m][n] + bv;
        *(f32x4*)&O[(size_t)row * 768 + colb] = v;
      }
    }
  } else if (MODE == 2) {
    // RoPE-Q: pairs (2i,2i+1) in-lane -> packed 8B stores
    unsigned short* qr = (unsigned short*)O0;
    const float2* t2 = (const float2*)tab;
    #pragma unroll
    for (int n = 0; n < 4; n++) {
      int col = cn + wc + n * 16 + lhi * 4;
      int hh = col >> 6, d0 = col & 63, i0 = d0 >> 1;
      #pragma unroll
      for (int m = 0; m < 4; m++) {
        int row = cm + wr + m * 16 + l15;
        int bb = row >> 12, np = row & 4095;
        float2 cs0 = t2[np * 32 + i0];
        float2 cs1 = t2[np * 32 + i0 + 1];
        f32x4 v = acc[m][n];
        ushort4v o;
        o[0] = f2bf(v[0] * cs0.x - v[1] * cs0.y);
        o[1] = f2bf(v[0] * cs0.y + v[1] * cs0.x);
        o[2] = f2bf(v[2] * cs1.x - v[3] * cs1.y);
        o[3] = f2bf(v[2] * cs1.y + v[3] * cs1.x);
        *(ushort4v*)(qr + ((size_t)(bb * 12 + hh) * 4096 + np) * 64 + d0) = o;
      }
    }
  } else if (MODE == 1) {
    // cols 0..767 -> K (RoPE, in-lane pairs), 768..1535 -> V (plain pack)
    unsigned short* kr = (unsigned short*)O0;
    unsigned short* vr = (unsigned short*)O1;
    const float2* t2 = (const float2*)tab;
    #pragma unroll
    for (int n = 0; n < 4; n++) {
      int col = cn + wc + n * 16 + lhi * 4;
      bool isk = (col < 768);
      int c2 = isk ? col : col - 768;
      int hh = c2 >> 6, d0 = c2 & 63, i0 = d0 >> 1;
      #pragma unroll
      for (int m = 0; m < 4; m++) {
        int row = cm + wr + m * 16 + l15;
        int bb = row >> 10, mm = row & 1023;
        f32x4 v = acc[m][n];
        size_t o = ((size_t)(bb * 12 + hh) * 1024 + mm) * 64 + d0;
        ushort4v pk;
        if (isk) {
          float2 cs0 = t2[mm * 32 + i0];
          float2 cs1 = t2[mm * 32 + i0 + 1];
          pk[0] = f2bf(v[0] * cs0.x - v[1] * cs0.y);
          pk[1] = f2bf(v[0] * cs0.y + v[1] * cs0.x);
          pk[2] = f2bf(v[2] * cs1.x - v[3] * cs1.y);
          pk[3] = f2bf(v[2] * cs1.y + v[3] * cs1.x);
          *(ushort4v*)(kr + o) = pk;
        } else {
          pk[0] = f2bf(v[0]); pk[1] = f2bf(v[1]);
          pk[2] = f2bf(v[2]); pk[3] = f2bf(v[3]);
          *(ushort4v*)(vr + o) = pk;
        }
      }
    }
  } else {
    // conv partial: plain bf16 pack, 8B stores
    unsigned short* O = (unsigned short*)O0 + (size_t)patch * 2048 * 768;
    #pragma unroll
    for (int n = 0; n < 4; n++) {
      int colb = cn + wc + n * 16 + lhi * 4;
      #pragma unroll
      for (int m = 0; m < 4; m++) {
        int row = cm + wr + m * 16 + l15;
        f32x4 v = acc[m][n];
        ushort4v pk;
        pk[0] = f2bf(v[0]); pk[1] = f2bf(v[1]);
        pk[2] = f2bf(v[2]); pk[3] = f2bf(v[3]);
        *(ushort4v*)(O + (size_t)row * 768 + colb) = pk;
      }
    }
  }
}

// ---------------- fused partial-reduce + bias + LayerNorm -> bf16 ----------------
__global__ __launch_bounds__(256) void k_lnr(const unsigned short* __restrict__ part,
    const float* __restrict__ srb, const float* __restrict__ g,
    const float* __restrict__ b, unsigned short* __restrict__ out) {
  int row = blockIdx.x;
  int t = threadIdx.x;
  float v[3];
  #pragma unroll
  for (int j = 0; j < 3; j++) {
    int c = t + j * 256;
    float s = srb[c];
    #pragma unroll
    for (int p = 0; p < 4; p++)
      s += bf2f(part[((size_t)p * 2048 + row) * 768 + c]);
    v[j] = s;
  }
  float s = v[0] + v[1] + v[2];
  float s2 = v[0] * v[0] + v[1] * v[1] + v[2] * v[2];
  #pragma unroll
  for (int off = 1; off < 64; off <<= 1) {
    s += __shfl_xor(s, off);
    s2 += __shfl_xor(s2, off);
  }
  __shared__ float ss[4], ss2[4];
  int w = t >> 6;
  if ((t & 63) == 0) { ss[w] = s; ss2[w] = s2; }
  __syncthreads();
  s = ss[0] + ss[1] + ss[2] + ss[3];
  s2 = ss2[0] + ss2[1] + ss2[2] + ss2[3];
  float mu = s * (1.0f / 768.0f);
  float var = s2 * (1.0f / 768.0f) - mu * mu;
  float rstd = rsqrtf(var + 1e-5f);
  unsigned short* o = out + (size_t)row * 768;
  #pragma unroll
  for (int j = 0; j < 3; j++) {
    int c = t + j * 256;
    o[c] = f2bf((v[j] - mu) * rstd * g[c] + b[c]);
  }
}

// ---------------- masked attention: per (b,h,64-query tile), bf16 out ----------------
__global__ __launch_bounds__(256) void k_attn(
    const unsigned short* __restrict__ qr,
    const unsigned short* __restrict__ kr,
    const unsigned short* __restrict__ vr,
    unsigned short* __restrict__ aout)
{
  __shared__ __align__(16) unsigned short kt_s[96][72];
  __shared__ __align__(16) unsigned short vt_s[64][104];
  __shared__ __align__(16) unsigned short p_s[4][16][104];

  const int qt = blockIdx.x;
  const int h = blockIdx.y;
  const int b = blockIdx.z;
  const int bh = b * 12 + h;
  const int tid = threadIdx.x, lane = tid & 63, w = tid >> 6;
  const int l15 = lane & 15, lhi = lane >> 4;

  const unsigned short* kg = kr + (size_t)bh * 1024 * 64;
  #pragma unroll
  for (int it = 0; it < 3; it++) {
    int ch = it * 256 + tid;
    int row = ch >> 3, c8 = (ch & 7) * 8;
    *(ushort8*)&kt_s[row][c8] = *(const ushort8*)(kg + row * 64 + c8);
  }
  const unsigned short* vg = vr + (size_t)bh * 1024 * 64;
  #pragma unroll
  for (int it = 0; it < 24; it++) {
    int e = it * 256 + tid;
    int row = e >> 6, d = e & 63;
    vt_s[d][row] = vg[row * 64 + d];
  }
  __syncthreads();

  const unsigned short* qg = qr + (size_t)bh * 4096 * 64
                           + (size_t)(qt * 64 + w * 16 + l15) * 64 + lhi * 8;
  short8 qf0 = *(const short8*)qg;
  short8 qf1 = *(const short8*)(qg + 32);

  f32x4 zero = {0.f, 0.f, 0.f, 0.f};
  f32x4 sacc[6];
  #pragma unroll
  for (int g = 0; g < 6; g++) sacc[g] = zero;
  #pragma unroll
  for (int g = 0; g < 6; g++) {
    short8 kf0 = *(const short8*)&kt_s[g * 16 + l15][lhi * 8];
    short8 kf1 = *(const short8*)&kt_s[g * 16 + l15][32 + lhi * 8];
    sacc[g] = __builtin_amdgcn_mfma_f32_16x16x32_bf16(qf0, kf0, sacc[g], 0, 0, 0);
    sacc[g] = __builtin_amdgcn_mfma_f32_16x16x32_bf16(qf1, kf1, sacc[g], 0, 0, 0);
  }

  int visv[4];
  #pragma unroll
  for (int r = 0; r < 4; r++) {
    int n = qt * 64 + w * 16 + lhi * 4 + r;
    visv[r] = 2 * (n >> 7) + (((n >> 6) + ((n & 63) << 6)) >> 7) + 1;
  }

  float mx[4] = {-INFINITY, -INFINITY, -INFINITY, -INFINITY};
  #pragma unroll
  for (int g = 0; g < 6; g++) {
    int key = g * 16 + l15;
    #pragma unroll
    for (int r = 0; r < 4; r++) {
      float s = (key < visv[r]) ? sacc[g][r] * 0.125f : -INFINITY;
      sacc[g][r] = s;
      mx[r] = fmaxf(mx[r], s);
    }
  }
  #pragma unroll
  for (int off = 1; off < 16; off <<= 1) {
    #pragma unroll
    for (int r = 0; r < 4; r++) mx[r] = fmaxf(mx[r], __shfl_xor(mx[r], off));
  }
  float sum[4] = {0.f, 0.f, 0.f, 0.f};
  #pragma unroll
  for (int g = 0; g < 6; g++) {
    #pragma unroll
    for (int r = 0; r < 4; r++) {
      float pv = __expf(sacc[g][r] - mx[r]);
      sum[r] += pv;
      p_s[w][lhi * 4 + r][g * 16 + l15] = f2bf(pv);
    }
  }
  #pragma unroll
  for (int off = 1; off < 16; off <<= 1) {
    #pragma unroll
    for (int r = 0; r < 4; r++) sum[r] += __shfl_xor(sum[r], off);
  }
  __syncthreads();

  f32x4 oacc[4];
  #pragma unroll
  for (int dg = 0; dg < 4; dg++) oacc[dg] = zero;
  #pragma unroll
  for (int ks = 0; ks < 3; ks++) {
    short8 pa = *(const short8*)&p_s[w][l15][ks * 32 + lhi * 8];
    #pragma unroll
    for (int dg = 0; dg < 4; dg++) {
      short8 vb = *(const short8*)&vt_s[dg * 16 + l15][ks * 32 + lhi * 8];
      oacc[dg] = __builtin_amdgcn_mfma_f32_16x16x32_bf16(pa, vb, oacc[dg], 0, 0, 0);
    }
  }

  unsigned short* ob = aout + ((size_t)b * 4096 + qt * 64 + w * 16) * 768 + h * 64;
  #pragma unroll
  for (int dg = 0; dg < 4; dg++) {
    int d = dg * 16 + l15;
    #pragma unroll
    for (int r = 0; r < 4; r++) {
      ob[(size_t)(lhi * 4 + r) * 768 + d] = f2bf(oacc[dg][r] / sum[r]);
    }
  }
}

extern "C" void kernel_launch(void* const* d_in, const int* in_sizes, int n_in,
                              void* d_out, int out_size, void* d_ws, size_t ws_size,
                              hipStream_t stream) {
  const float* x   = (const float*)d_in[0];
  const float* Wq  = (const float*)d_in[1];
  const float* Wkv = (const float*)d_in[2];
  const float* srw = (const float*)d_in[3];
  const float* srb = (const float*)d_in[4];
  const float* lng = (const float*)d_in[5];
  const float* lnb = (const float*)d_in[6];
  const float* pw  = (const float*)d_in[7];
  const float* pb  = (const float*)d_in[8];

  char* ws = (char*)d_ws;
  float* qtab           = (float*)(ws);
  float* ktab           = (float*)(ws + 1048576);
  unsigned short* xb    = (unsigned short*)(ws + 1310720);    // bf16 x; attn_out later
  unsigned short* attno = xb;
  unsigned short* qrope = (unsigned short*)(ws + 13893632);
  unsigned short* part  = (unsigned short*)(ws + 26476544);   // [4][2048][768] bf16
  unsigned short* kr    = (unsigned short*)(ws + 26476544);   // overlays part (dead)
  unsigned short* vr    = (unsigned short*)(ws + 29622272);
  unsigned short* wqb   = (unsigned short*)(ws + 39059456);
  unsigned short* wkvb  = (unsigned short*)(ws + 40239104);
  unsigned short* pwb   = (unsigned short*)(ws + 42598400);
  unsigned short* wsrb  = (unsigned short*)(ws + 43778048);   // [4][768][768] bf16
  unsigned short* xrn   = (unsigned short*)(ws + 48496640);   // [2048][768] bf16

  k_prep<<<18304, 256, 0, stream>>>(x, Wq, Wkv, pw, srw, qtab, ktab,
                                    xb, wqb, wkvb, pwb, wsrb);
  k_g<2><<<384, 256, 0, stream>>>(xb, wqb, qrope, nullptr, nullptr, qtab);
  k_g<3><<<384, 256, 0, stream>>>(xb, wsrb, part, nullptr, nullptr, nullptr);
  k_lnr<<<2048, 256, 0, stream>>>(part, srb, lng, lnb, xrn);
  k_g<1><<<192, 256, 0, stream>>>(xrn, wkvb, kr, vr, nullptr, ktab);
  k_attn<<<dim3(64, 12, 2), 256, 0, stream>>>(qrope, kr, vr, attno);
  k_g<0><<<384, 256, 0, stream>>>(attno, pwb, d_out, nullptr, pb, nullptr);
}